// Round 1
// baseline (1962.771 us; speedup 1.0000x reference)
//
#include <hip/hip_runtime.h>

// GCN 2-layer forward (Hu et al. mol-GNN variant), fp32.
// Inputs: x[N,64], edge_index[2,E] (int32), edge_attr[E,2] (int32),
//         W1[64,64], b1[64], ebond1[6,64], edir1[3,64], W2, b2, ebond2, edir2.
// Output: [N,64] fp32.
//
// Structure:
//   dis[n] = 1/sqrt(1 + #outgoing edges from n)      (self-loop included)
//   per layer: h = X@W.T + b
//              out[n]  = dis[n]^2 * (h[n] + ebond[4] + edir[0])   (self-loop init)
//              out[d] += dis[s]*dis[d] * (h[s] + ebond[bt] + edir[bd])  for each edge
//   ReLU applied when reading layer-1 output into GEMM2.

#define THREADS 256

__global__ __launch_bounds__(THREADS) void init_deg_kernel(float* __restrict__ deg, int N) {
    int i = blockIdx.x * THREADS + threadIdx.x;
    if (i < N) deg[i] = 1.0f;  // self-loop
}

__global__ __launch_bounds__(THREADS) void count_deg_kernel(const int* __restrict__ src,
                                                            float* __restrict__ deg, int E) {
    int i = blockIdx.x * THREADS + threadIdx.x;
    if (i < E) atomicAdd(&deg[src[i]], 1.0f);
}

__global__ __launch_bounds__(THREADS) void rsqrt_deg_kernel(float* __restrict__ deg, int N) {
    int i = blockIdx.x * THREADS + threadIdx.x;
    if (i < N) {
        float v = deg[i];
        deg[i] = (v > 0.0f) ? (1.0f / sqrtf(v)) : 0.0f;
    }
}

// H[row, j] = B[j] + sum_k X[row,k] * W[j,k]   (X @ W.T + b)
// One row per thread; x row held in 64 VGPRs; W/B indices are wave-uniform so
// the compiler can scalarize them to s_load + v_fma with SGPR operand.
template <bool RELU_IN>
__global__ __launch_bounds__(THREADS) void gemm64_kernel(const float* __restrict__ X,
                                                         const float* __restrict__ W,
                                                         const float* __restrict__ B,
                                                         float* __restrict__ H, int N) {
    int row = blockIdx.x * THREADS + threadIdx.x;
    if (row >= N) return;
    float xr[64];
    const float4* xp = (const float4*)(X + (size_t)row * 64);
#pragma unroll
    for (int m = 0; m < 16; ++m) {
        float4 v = xp[m];
        if (RELU_IN) {
            v.x = fmaxf(v.x, 0.0f);
            v.y = fmaxf(v.y, 0.0f);
            v.z = fmaxf(v.z, 0.0f);
            v.w = fmaxf(v.w, 0.0f);
        }
        xr[4 * m + 0] = v.x;
        xr[4 * m + 1] = v.y;
        xr[4 * m + 2] = v.z;
        xr[4 * m + 3] = v.w;
    }
    float* hp = H + (size_t)row * 64;
#pragma unroll 1
    for (int j4 = 0; j4 < 64; j4 += 4) {
        float4 a = make_float4(B[j4 + 0], B[j4 + 1], B[j4 + 2], B[j4 + 3]);
#pragma unroll
        for (int k = 0; k < 64; ++k) {
            float xk = xr[k];
            a.x = fmaf(xk, W[(j4 + 0) * 64 + k], a.x);
            a.y = fmaf(xk, W[(j4 + 1) * 64 + k], a.y);
            a.z = fmaf(xk, W[(j4 + 2) * 64 + k], a.z);
            a.w = fmaf(xk, W[(j4 + 3) * 64 + k], a.w);
        }
        *(float4*)(hp + j4) = a;
    }
}

// out[n] = dis[n]^2 * (H[n] + ebond[4] + edir[0])  — self-loop contribution,
// doubles as the initializer for the aggregation buffer.
__global__ __launch_bounds__(THREADS) void self_loop_kernel(const float* __restrict__ H,
                                                            const float* __restrict__ dis,
                                                            const float* __restrict__ ebond,
                                                            const float* __restrict__ edir,
                                                            float* __restrict__ out, int N) {
    int tid = blockIdx.x * THREADS + threadIdx.x;
    int n = tid >> 4;
    if (n >= N) return;
    int c = (tid & 15) << 2;
    float s = dis[n];
    float nrm = s * s;
    float4 hv = *(const float4*)(H + (size_t)n * 64 + c);
    float4 eb = *(const float4*)(ebond + 4 * 64 + c);
    float4 ed = *(const float4*)(edir + c);
    float4 o;
    o.x = nrm * (hv.x + eb.x + ed.x);
    o.y = nrm * (hv.y + eb.y + ed.y);
    o.z = nrm * (hv.z + eb.z + ed.z);
    o.w = nrm * (hv.w + eb.w + ed.w);
    *(float4*)(out + (size_t)n * 64 + c) = o;
}

// out[dst[e]] += dis[src]*dis[dst] * (H[src] + ebond[bt] + edir[bd])
// 16 threads per edge, 4 dims per thread, scalar fp32 atomics.
__global__ __launch_bounds__(THREADS) void scatter_edges_kernel(const float* __restrict__ H,
                                                                const float* __restrict__ dis,
                                                                const float* __restrict__ ebond,
                                                                const float* __restrict__ edir,
                                                                const int* __restrict__ src,
                                                                const int* __restrict__ dst,
                                                                const int* __restrict__ attr,
                                                                float* __restrict__ out, int E) {
    int tid = blockIdx.x * THREADS + threadIdx.x;
    int e = tid >> 4;
    if (e >= E) return;
    int c = (tid & 15) << 2;
    int s = src[e];
    int d = dst[e];
    int bt = attr[2 * e];
    int bd = attr[2 * e + 1];
    float nrm = dis[s] * dis[d];
    float4 hv = *(const float4*)(H + (size_t)s * 64 + c);
    float4 eb = *(const float4*)(ebond + (size_t)bt * 64 + c);
    float4 ed = *(const float4*)(edir + (size_t)bd * 64 + c);
    float* o = out + (size_t)d * 64 + c;
    atomicAdd(o + 0, nrm * (hv.x + eb.x + ed.x));
    atomicAdd(o + 1, nrm * (hv.y + eb.y + ed.y));
    atomicAdd(o + 2, nrm * (hv.z + eb.z + ed.z));
    atomicAdd(o + 3, nrm * (hv.w + eb.w + ed.w));
}

extern "C" void kernel_launch(void* const* d_in, const int* in_sizes, int n_in,
                              void* d_out, int out_size, void* d_ws, size_t ws_size,
                              hipStream_t stream) {
    const float* x      = (const float*)d_in[0];
    const int*   eidx   = (const int*)d_in[1];
    const int*   eattr  = (const int*)d_in[2];
    const float* W1     = (const float*)d_in[3];
    const float* b1     = (const float*)d_in[4];
    const float* ebond1 = (const float*)d_in[5];
    const float* edir1  = (const float*)d_in[6];
    const float* W2     = (const float*)d_in[7];
    const float* b2     = (const float*)d_in[8];
    const float* ebond2 = (const float*)d_in[9];
    const float* edir2  = (const float*)d_in[10];

    const int N = in_sizes[0] / 64;
    const int E = in_sizes[1] / 2;
    const int* src = eidx;
    const int* dst = eidx + E;

    float* ws   = (float*)d_ws;
    size_t offA = ((size_t)N + 63) & ~(size_t)63;   // dis occupies [0, N)
    float* dis  = ws;
    float* bufA = ws + offA;                        // h (linear) buffer
    float* bufB = bufA + (size_t)N * 64;            // layer-1 aggregated output

    float* out = (float*)d_out;

    const int gN   = (N + THREADS - 1) / THREADS;
    const int gE   = (E + THREADS - 1) / THREADS;
    const int gN16 = (N * 16 + THREADS - 1) / THREADS;
    const int gE16 = ((E > (1 << 27) ? 0 : E * 16) + THREADS - 1) / THREADS;  // E*16 fits int here

    // degree -> dis
    init_deg_kernel<<<gN, THREADS, 0, stream>>>(dis, N);
    count_deg_kernel<<<gE, THREADS, 0, stream>>>(src, dis, E);
    rsqrt_deg_kernel<<<gN, THREADS, 0, stream>>>(dis, N);

    // layer 1
    gemm64_kernel<false><<<gN, THREADS, 0, stream>>>(x, W1, b1, bufA, N);
    self_loop_kernel<<<gN16, THREADS, 0, stream>>>(bufA, dis, ebond1, edir1, bufB, N);
    scatter_edges_kernel<<<gE16, THREADS, 0, stream>>>(bufA, dis, ebond1, edir1, src, dst, eattr,
                                                       bufB, E);

    // layer 2 (ReLU fused into GEMM input read)
    gemm64_kernel<true><<<gN, THREADS, 0, stream>>>(bufB, W2, b2, bufA, N);
    self_loop_kernel<<<gN16, THREADS, 0, stream>>>(bufA, dis, ebond2, edir2, out, N);
    scatter_edges_kernel<<<gE16, THREADS, 0, stream>>>(bufA, dis, ebond2, edir2, src, dst, eattr,
                                                       out, E);
}

// Round 3
// 474.058 us; speedup vs baseline: 4.1404x; 4.1404x over previous
//
#include <hip/hip_runtime.h>

// GCN 2-layer forward (Hu et al. mol-GNN variant), fp32 — CSR aggregation, no fp32 atomics.
//
//   dis[n] = 1/sqrt(1 + outdeg(n))
//   per layer: h = X@W.T + b
//              out[n] = dis[n]^2*(h[n]+ebond[4]+edir[0]) + sum_{e: dst=n} dis[s]*dis[n]*(h[s]+emb_e)
//   ReLU fused into GEMM2 input read.
//
// Workspace budget note: ws_size is finite (R1's 51.6 MB layout passed; R2's 61.2 MB
// corrupted adjacent allocations). This layout needs ~31.6 MB:
//   dis/src_deg/dst_cnt/row_ptr/cursor (5 x 400KB) + bsum + entries (4MB) + bufA (25.6MB).
// Layer-1 aggregate goes directly into d_out (then read back by GEMM2 with fused ReLU).

#define THREADS 256

__global__ __launch_bounds__(THREADS) void zero_counts_kernel(int* __restrict__ a,
                                                              int* __restrict__ b, int N) {
    int i = blockIdx.x * THREADS + threadIdx.x;
    if (i < N) { a[i] = 0; b[i] = 0; }
}

__global__ __launch_bounds__(THREADS) void histogram_kernel(const int* __restrict__ src,
                                                            const int* __restrict__ dst,
                                                            int* __restrict__ src_deg,
                                                            int* __restrict__ dst_cnt, int E) {
    int i = blockIdx.x * THREADS + threadIdx.x;
    if (i < E) {
        atomicAdd(&src_deg[src[i]], 1);
        atomicAdd(&dst_cnt[dst[i]], 1);
    }
}

__global__ __launch_bounds__(THREADS) void dis_kernel(const int* __restrict__ src_deg,
                                                      float* __restrict__ dis, int N) {
    int i = blockIdx.x * THREADS + threadIdx.x;
    if (i < N) dis[i] = 1.0f / sqrtf(1.0f + (float)src_deg[i]);
}

// Block-local exclusive scan: block b handles cnt[b*1024 .. b*1024+1023], 4 elems/thread.
__global__ __launch_bounds__(THREADS) void scan1_kernel(const int* __restrict__ cnt,
                                                        int* __restrict__ row_ptr,
                                                        int* __restrict__ bsum, int N) {
    __shared__ int s[THREADS];
    int t = threadIdx.x;
    int base = blockIdx.x * 1024 + t * 4;
    int v[4];
#pragma unroll
    for (int k = 0; k < 4; ++k) v[k] = (base + k < N) ? cnt[base + k] : 0;
    int sum4 = v[0] + v[1] + v[2] + v[3];
    s[t] = sum4;
    __syncthreads();
    for (int d = 1; d < THREADS; d <<= 1) {
        int add = (t >= d) ? s[t - d] : 0;
        __syncthreads();
        s[t] += add;
        __syncthreads();
    }
    int off = (t == 0) ? 0 : s[t - 1];
#pragma unroll
    for (int k = 0; k < 4; ++k) {
        if (base + k < N) row_ptr[base + k] = off;
        off += v[k];
    }
    if (t == THREADS - 1) bsum[blockIdx.x] = s[THREADS - 1];
}

// Single-block exclusive scan of block sums (nb <= 256).
__global__ __launch_bounds__(THREADS) void scan2_kernel(int* __restrict__ bsum, int nb) {
    __shared__ int s[THREADS];
    int t = threadIdx.x;
    s[t] = (t < nb) ? bsum[t] : 0;
    __syncthreads();
    for (int d = 1; d < THREADS; d <<= 1) {
        int add = (t >= d) ? s[t - d] : 0;
        __syncthreads();
        s[t] += add;
        __syncthreads();
    }
    if (t < nb) bsum[t] = (t == 0) ? 0 : s[t - 1];
}

__global__ __launch_bounds__(THREADS) void scan3_kernel(int* __restrict__ row_ptr,
                                                        const int* __restrict__ bsum,
                                                        int* __restrict__ cursor, int N) {
    int i = blockIdx.x * THREADS + threadIdx.x;
    if (i < N) {
        int r = row_ptr[i] + bsum[i >> 10];
        row_ptr[i] = r;
        cursor[i] = r;
    }
}

// entries[pos] = src | (embIdx << 17)   (src < 2^17, embIdx = bt*3+bd < 18)
__global__ __launch_bounds__(THREADS) void fill_kernel(const int* __restrict__ src,
                                                       const int* __restrict__ dst,
                                                       const int* __restrict__ attr,
                                                       int* __restrict__ cursor,
                                                       int* __restrict__ entries, int E) {
    int e = blockIdx.x * THREADS + threadIdx.x;
    if (e >= E) return;
    int s = src[e];
    int d = dst[e];
    int bt = attr[2 * e];
    int bd = attr[2 * e + 1];
    int pos = atomicAdd(&cursor[d], 1);
    entries[pos] = s | ((bt * 3 + bd) << 17);
}

// H[row, j] = B[j] + sum_k X[row,k] * W[j,k]   (X @ W.T + b); one row per thread.
template <bool RELU_IN>
__global__ __launch_bounds__(THREADS) void gemm64_kernel(const float* __restrict__ X,
                                                         const float* __restrict__ W,
                                                         const float* __restrict__ B,
                                                         float* __restrict__ H, int N) {
    int row = blockIdx.x * THREADS + threadIdx.x;
    if (row >= N) return;
    float xr[64];
    const float4* xp = (const float4*)(X + (size_t)row * 64);
#pragma unroll
    for (int m = 0; m < 16; ++m) {
        float4 v = xp[m];
        if (RELU_IN) {
            v.x = fmaxf(v.x, 0.0f);
            v.y = fmaxf(v.y, 0.0f);
            v.z = fmaxf(v.z, 0.0f);
            v.w = fmaxf(v.w, 0.0f);
        }
        xr[4 * m + 0] = v.x;
        xr[4 * m + 1] = v.y;
        xr[4 * m + 2] = v.z;
        xr[4 * m + 3] = v.w;
    }
    float* hp = H + (size_t)row * 64;
#pragma unroll 1
    for (int j4 = 0; j4 < 64; j4 += 4) {
        float4 a = make_float4(B[j4 + 0], B[j4 + 1], B[j4 + 2], B[j4 + 3]);
#pragma unroll
        for (int k = 0; k < 64; ++k) {
            float xk = xr[k];
            a.x = fmaf(xk, W[(j4 + 0) * 64 + k], a.x);
            a.y = fmaf(xk, W[(j4 + 1) * 64 + k], a.y);
            a.z = fmaf(xk, W[(j4 + 2) * 64 + k], a.z);
            a.w = fmaf(xk, W[(j4 + 3) * 64 + k], a.w);
        }
        *(float4*)(hp + j4) = a;
    }
}

// out[n] = dis[n]^2*(H[n]+embc[12]) + sum_k dis[s]*dis[n]*(H[s]+embc[ei])
// 16 threads/node, 4 dims each.
__global__ __launch_bounds__(THREADS) void aggregate_kernel(const float* __restrict__ H,
                                                            const float* __restrict__ dis,
                                                            const float* __restrict__ ebond,
                                                            const float* __restrict__ edir,
                                                            const int* __restrict__ row_ptr,
                                                            const int* __restrict__ cnt,
                                                            const int* __restrict__ entries,
                                                            float* __restrict__ out, int N) {
    __shared__ float embc[18][64];
    int t = threadIdx.x;
    for (int i = t; i < 18 * 64; i += THREADS) {
        int row = i >> 6, c = i & 63;
        embc[row][c] = ebond[(row / 3) * 64 + c] + edir[(row % 3) * 64 + c];
    }
    __syncthreads();

    int n = blockIdx.x * 16 + (t >> 4);
    if (n >= N) return;
    int c = (t & 15) << 2;

    float dn = dis[n];
    float4 hv = *(const float4*)(H + (size_t)n * 64 + c);
    float4 em = *(const float4*)(&embc[12][c]);  // self-loop: bt=4, bd=0 -> 4*3+0
    float nrm = dn * dn;
    float4 acc;
    acc.x = nrm * (hv.x + em.x);
    acc.y = nrm * (hv.y + em.y);
    acc.z = nrm * (hv.z + em.z);
    acc.w = nrm * (hv.w + em.w);

    int start = row_ptr[n];
    int end = start + cnt[n];
    for (int p = start; p < end; ++p) {
        int ent = entries[p];
        int s = ent & 0x1FFFF;
        int ei = ent >> 17;
        float w = dis[s] * dn;
        float4 h = *(const float4*)(H + (size_t)s * 64 + c);
        float4 e = *(const float4*)(&embc[ei][c]);
        acc.x = fmaf(w, h.x + e.x, acc.x);
        acc.y = fmaf(w, h.y + e.y, acc.y);
        acc.z = fmaf(w, h.z + e.z, acc.z);
        acc.w = fmaf(w, h.w + e.w, acc.w);
    }
    *(float4*)(out + (size_t)n * 64 + c) = acc;
}

extern "C" void kernel_launch(void* const* d_in, const int* in_sizes, int n_in,
                              void* d_out, int out_size, void* d_ws, size_t ws_size,
                              hipStream_t stream) {
    const float* x      = (const float*)d_in[0];
    const int*   eidx   = (const int*)d_in[1];
    const int*   eattr  = (const int*)d_in[2];
    const float* W1     = (const float*)d_in[3];
    const float* b1     = (const float*)d_in[4];
    const float* ebond1 = (const float*)d_in[5];
    const float* edir1  = (const float*)d_in[6];
    const float* W2     = (const float*)d_in[7];
    const float* b2     = (const float*)d_in[8];
    const float* ebond2 = (const float*)d_in[9];
    const float* edir2  = (const float*)d_in[10];

    const int N = in_sizes[0] / 64;
    const int E = in_sizes[1] / 2;
    const int* src = eidx;
    const int* dst = eidx + E;
    float* out = (float*)d_out;

    // Workspace layout (~31.6 MB total; ws proven >= ~51.6 MB in R1).
    char* w = (char*)d_ws;
    size_t Na = ((size_t)N * 4 + 255) & ~(size_t)255;
    size_t Ea = ((size_t)E * 4 + 255) & ~(size_t)255;
    float* dis     = (float*)w;            w += Na;
    int*   src_deg = (int*)w;              w += Na;
    int*   dst_cnt = (int*)w;              w += Na;
    int*   row_ptr = (int*)w;              w += Na;
    int*   cursor  = (int*)w;              w += Na;
    int*   bsum    = (int*)w;              w += 4096;
    int*   entries = (int*)w;              w += Ea;
    float* bufA    = (float*)w;            w += (size_t)N * 64 * 4;  // h (linear out)

    const int gN   = (N + THREADS - 1) / THREADS;
    const int gE   = (E + THREADS - 1) / THREADS;
    const int gN16 = (N + 15) / 16;  // aggregate: 16 nodes/block
    const int nb   = (N + 1023) / 1024;

    // CSR build (graph shared by both layers)
    zero_counts_kernel<<<gN, THREADS, 0, stream>>>(src_deg, dst_cnt, N);
    histogram_kernel<<<gE, THREADS, 0, stream>>>(src, dst, src_deg, dst_cnt, E);
    dis_kernel<<<gN, THREADS, 0, stream>>>(src_deg, dis, N);
    scan1_kernel<<<nb, THREADS, 0, stream>>>(dst_cnt, row_ptr, bsum, N);
    scan2_kernel<<<1, THREADS, 0, stream>>>(bsum, nb);
    scan3_kernel<<<gN, THREADS, 0, stream>>>(row_ptr, bsum, cursor, N);
    fill_kernel<<<gE, THREADS, 0, stream>>>(src, dst, eattr, cursor, entries, E);

    // layer 1: h -> bufA, aggregate -> d_out (used as temp)
    gemm64_kernel<false><<<gN, THREADS, 0, stream>>>(x, W1, b1, bufA, N);
    aggregate_kernel<<<gN16, THREADS, 0, stream>>>(bufA, dis, ebond1, edir1, row_ptr, dst_cnt,
                                                   entries, out, N);

    // layer 2 (ReLU fused into GEMM input read): out -> bufA -> out
    gemm64_kernel<true><<<gN, THREADS, 0, stream>>>(out, W2, b2, bufA, N);
    aggregate_kernel<<<gN16, THREADS, 0, stream>>>(bufA, dis, ebond2, edir2, row_ptr, dst_cnt,
                                                   entries, out, N);
}

// Round 4
// 431.038 us; speedup vs baseline: 4.5536x; 1.0998x over previous
//
#include <hip/hip_runtime.h>

// GCN 2-layer forward (Hu et al. mol-GNN variant), fp32 — CSR aggregation, no fp32 atomics.
//
//   dis[n] = 1/sqrt(1 + outdeg(n))
//   per layer: h = X@W.T + b
//              out[n] = dis[n]^2*(h[n]+ebond[4]+edir[0]) + sum_{e: dst=n} dis[s]*dis[n]*(h[s]+emb_e)
//   ReLU fused into GEMM2 input read.
//
// Workspace budget: ws_size is finite (R1's 51.6 MB passed; R2's 61.2 MB corrupted
// neighboring allocations). This layout needs ~31.6 MB. Layer-1 aggregate goes into
// d_out; GEMM2 reads it back with fused ReLU.
//
// GEMM v2 (R4): 4-wave blocks, 64-row tile. Wave w computes cols [w*16, w*16+16);
// W/B indices wave-uniform (readfirstlane) -> scalar s_loads + SGPR-operand FMAs.
// Output staged through padded LDS tile so every global store is wave-contiguous
// (R3 showed 3.4x HBM write amplification from strided partial-line stores).

#define THREADS 256

__global__ __launch_bounds__(THREADS) void zero_counts_kernel(int* __restrict__ a,
                                                              int* __restrict__ b, int N) {
    int i = blockIdx.x * THREADS + threadIdx.x;
    if (i < N) { a[i] = 0; b[i] = 0; }
}

__global__ __launch_bounds__(THREADS) void histogram_kernel(const int* __restrict__ src,
                                                            const int* __restrict__ dst,
                                                            int* __restrict__ src_deg,
                                                            int* __restrict__ dst_cnt, int E) {
    int i = blockIdx.x * THREADS + threadIdx.x;
    if (i < E) {
        atomicAdd(&src_deg[src[i]], 1);
        atomicAdd(&dst_cnt[dst[i]], 1);
    }
}

__global__ __launch_bounds__(THREADS) void dis_kernel(const int* __restrict__ src_deg,
                                                      float* __restrict__ dis, int N) {
    int i = blockIdx.x * THREADS + threadIdx.x;
    if (i < N) dis[i] = 1.0f / sqrtf(1.0f + (float)src_deg[i]);
}

// Block-local exclusive scan: block b handles cnt[b*1024 .. b*1024+1023], 4 elems/thread.
__global__ __launch_bounds__(THREADS) void scan1_kernel(const int* __restrict__ cnt,
                                                        int* __restrict__ row_ptr,
                                                        int* __restrict__ bsum, int N) {
    __shared__ int s[THREADS];
    int t = threadIdx.x;
    int base = blockIdx.x * 1024 + t * 4;
    int v[4];
#pragma unroll
    for (int k = 0; k < 4; ++k) v[k] = (base + k < N) ? cnt[base + k] : 0;
    int sum4 = v[0] + v[1] + v[2] + v[3];
    s[t] = sum4;
    __syncthreads();
    for (int d = 1; d < THREADS; d <<= 1) {
        int add = (t >= d) ? s[t - d] : 0;
        __syncthreads();
        s[t] += add;
        __syncthreads();
    }
    int off = (t == 0) ? 0 : s[t - 1];
#pragma unroll
    for (int k = 0; k < 4; ++k) {
        if (base + k < N) row_ptr[base + k] = off;
        off += v[k];
    }
    if (t == THREADS - 1) bsum[blockIdx.x] = s[THREADS - 1];
}

// Single-block exclusive scan of block sums (nb <= 256).
__global__ __launch_bounds__(THREADS) void scan2_kernel(int* __restrict__ bsum, int nb) {
    __shared__ int s[THREADS];
    int t = threadIdx.x;
    s[t] = (t < nb) ? bsum[t] : 0;
    __syncthreads();
    for (int d = 1; d < THREADS; d <<= 1) {
        int add = (t >= d) ? s[t - d] : 0;
        __syncthreads();
        s[t] += add;
        __syncthreads();
    }
    if (t < nb) bsum[t] = (t == 0) ? 0 : s[t - 1];
}

__global__ __launch_bounds__(THREADS) void scan3_kernel(int* __restrict__ row_ptr,
                                                        const int* __restrict__ bsum,
                                                        int* __restrict__ cursor, int N) {
    int i = blockIdx.x * THREADS + threadIdx.x;
    if (i < N) {
        int r = row_ptr[i] + bsum[i >> 10];
        row_ptr[i] = r;
        cursor[i] = r;
    }
}

// entries[pos] = src | (embIdx << 17)   (src < 2^17, embIdx = bt*3+bd < 18)
__global__ __launch_bounds__(THREADS) void fill_kernel(const int* __restrict__ src,
                                                       const int* __restrict__ dst,
                                                       const int* __restrict__ attr,
                                                       int* __restrict__ cursor,
                                                       int* __restrict__ entries, int E) {
    int e = blockIdx.x * THREADS + threadIdx.x;
    if (e >= E) return;
    int s = src[e];
    int d = dst[e];
    int bt = attr[2 * e];
    int bd = attr[2 * e + 1];
    int pos = atomicAdd(&cursor[d], 1);
    entries[pos] = s | ((bt * 3 + bd) << 17);
}

// H = X @ W.T + B. Block = 4 waves = 64-row tile; wave w owns cols [16w, 16w+16).
// W/B reads are wave-uniform -> scalar loads; stores staged via LDS for coalescing.
template <bool RELU_IN>
__global__ __launch_bounds__(THREADS) void gemm64_kernel(const float* __restrict__ X,
                                                         const float* __restrict__ W,
                                                         const float* __restrict__ B,
                                                         float* __restrict__ H, int N) {
    __shared__ float smem[64][68];  // +4 pad keeps 16B alignment, breaks bank aliasing
    int t = threadIdx.x;
    int lane = t & 63;
    int wave = __builtin_amdgcn_readfirstlane(t >> 6);  // force wave-uniform
    int row = blockIdx.x * 64 + lane;

    const float* Wp = W + wave * (16 * 64);  // uniform: 16 rows of W for this wave
    const float* Bp = B + wave * 16;

    float xr[64];
    if (row < N) {
        const float4* xp = (const float4*)(X + (size_t)row * 64);
#pragma unroll
        for (int m = 0; m < 16; ++m) {
            float4 v = xp[m];
            if (RELU_IN) {
                v.x = fmaxf(v.x, 0.0f);
                v.y = fmaxf(v.y, 0.0f);
                v.z = fmaxf(v.z, 0.0f);
                v.w = fmaxf(v.w, 0.0f);
            }
            xr[4 * m + 0] = v.x;
            xr[4 * m + 1] = v.y;
            xr[4 * m + 2] = v.z;
            xr[4 * m + 3] = v.w;
        }
    } else {
#pragma unroll
        for (int k = 0; k < 64; ++k) xr[k] = 0.0f;
    }

    float acc[16];
#pragma unroll
    for (int j = 0; j < 16; ++j) acc[j] = Bp[j];

#pragma unroll
    for (int k = 0; k < 64; ++k) {
        float xk = xr[k];
#pragma unroll
        for (int j = 0; j < 16; ++j) acc[j] = fmaf(xk, Wp[j * 64 + k], acc[j]);
    }

    // stage to LDS: row = lane, cols 16w..16w+15
#pragma unroll
    for (int j4 = 0; j4 < 4; ++j4) {
        *(float4*)(&smem[lane][wave * 16 + j4 * 4]) =
            make_float4(acc[4 * j4], acc[4 * j4 + 1], acc[4 * j4 + 2], acc[4 * j4 + 3]);
    }
    __syncthreads();

    // coalesced store: 1024 float4s, 4 per thread; wave covers contiguous 1KB
#pragma unroll
    for (int i = 0; i < 4; ++i) {
        int idx = t + i * THREADS;
        int r = idx >> 4;
        int c = (idx & 15) << 2;
        int grow = blockIdx.x * 64 + r;
        if (grow < N) *(float4*)(H + (size_t)grow * 64 + c) = *(const float4*)(&smem[r][c]);
    }
}

// out[n] = dis[n]^2*(H[n]+embc[12]) + sum_k dis[s]*dis[n]*(H[s]+embc[ei])
// 16 threads/node, 4 dims each.
__global__ __launch_bounds__(THREADS) void aggregate_kernel(const float* __restrict__ H,
                                                            const float* __restrict__ dis,
                                                            const float* __restrict__ ebond,
                                                            const float* __restrict__ edir,
                                                            const int* __restrict__ row_ptr,
                                                            const int* __restrict__ cnt,
                                                            const int* __restrict__ entries,
                                                            float* __restrict__ out, int N) {
    __shared__ float embc[18][64];
    int t = threadIdx.x;
    for (int i = t; i < 18 * 64; i += THREADS) {
        int row = i >> 6, c = i & 63;
        embc[row][c] = ebond[(row / 3) * 64 + c] + edir[(row % 3) * 64 + c];
    }
    __syncthreads();

    int n = blockIdx.x * 16 + (t >> 4);
    if (n >= N) return;
    int c = (t & 15) << 2;

    float dn = dis[n];
    float4 hv = *(const float4*)(H + (size_t)n * 64 + c);
    float4 em = *(const float4*)(&embc[12][c]);  // self-loop: bt=4, bd=0 -> 4*3+0
    float nrm = dn * dn;
    float4 acc;
    acc.x = nrm * (hv.x + em.x);
    acc.y = nrm * (hv.y + em.y);
    acc.z = nrm * (hv.z + em.z);
    acc.w = nrm * (hv.w + em.w);

    int start = row_ptr[n];
    int end = start + cnt[n];
    for (int p = start; p < end; ++p) {
        int ent = entries[p];
        int s = ent & 0x1FFFF;
        int ei = ent >> 17;
        float w = dis[s] * dn;
        float4 h = *(const float4*)(H + (size_t)s * 64 + c);
        float4 e = *(const float4*)(&embc[ei][c]);
        acc.x = fmaf(w, h.x + e.x, acc.x);
        acc.y = fmaf(w, h.y + e.y, acc.y);
        acc.z = fmaf(w, h.z + e.z, acc.z);
        acc.w = fmaf(w, h.w + e.w, acc.w);
    }
    *(float4*)(out + (size_t)n * 64 + c) = acc;
}

extern "C" void kernel_launch(void* const* d_in, const int* in_sizes, int n_in,
                              void* d_out, int out_size, void* d_ws, size_t ws_size,
                              hipStream_t stream) {
    const float* x      = (const float*)d_in[0];
    const int*   eidx   = (const int*)d_in[1];
    const int*   eattr  = (const int*)d_in[2];
    const float* W1     = (const float*)d_in[3];
    const float* b1     = (const float*)d_in[4];
    const float* ebond1 = (const float*)d_in[5];
    const float* edir1  = (const float*)d_in[6];
    const float* W2     = (const float*)d_in[7];
    const float* b2     = (const float*)d_in[8];
    const float* ebond2 = (const float*)d_in[9];
    const float* edir2  = (const float*)d_in[10];

    const int N = in_sizes[0] / 64;
    const int E = in_sizes[1] / 2;
    const int* src = eidx;
    const int* dst = eidx + E;
    float* out = (float*)d_out;

    // Workspace layout (~31.6 MB total).
    char* w = (char*)d_ws;
    size_t Na = ((size_t)N * 4 + 255) & ~(size_t)255;
    size_t Ea = ((size_t)E * 4 + 255) & ~(size_t)255;
    float* dis     = (float*)w;            w += Na;
    int*   src_deg = (int*)w;              w += Na;
    int*   dst_cnt = (int*)w;              w += Na;
    int*   row_ptr = (int*)w;              w += Na;
    int*   cursor  = (int*)w;              w += Na;
    int*   bsum    = (int*)w;              w += 4096;
    int*   entries = (int*)w;              w += Ea;
    float* bufA    = (float*)w;            w += (size_t)N * 64 * 4;  // h (linear out)

    const int gN   = (N + THREADS - 1) / THREADS;
    const int gE   = (E + THREADS - 1) / THREADS;
    const int gG   = (N + 63) / 64;   // gemm: 64 rows/block
    const int gN16 = (N + 15) / 16;   // aggregate: 16 nodes/block
    const int nb   = (N + 1023) / 1024;

    // CSR build (graph shared by both layers)
    zero_counts_kernel<<<gN, THREADS, 0, stream>>>(src_deg, dst_cnt, N);
    histogram_kernel<<<gE, THREADS, 0, stream>>>(src, dst, src_deg, dst_cnt, E);
    dis_kernel<<<gN, THREADS, 0, stream>>>(src_deg, dis, N);
    scan1_kernel<<<nb, THREADS, 0, stream>>>(dst_cnt, row_ptr, bsum, N);
    scan2_kernel<<<1, THREADS, 0, stream>>>(bsum, nb);
    scan3_kernel<<<gN, THREADS, 0, stream>>>(row_ptr, bsum, cursor, N);
    fill_kernel<<<gE, THREADS, 0, stream>>>(src, dst, eattr, cursor, entries, E);

    // layer 1: h -> bufA, aggregate -> d_out (used as temp)
    gemm64_kernel<false><<<gG, THREADS, 0, stream>>>(x, W1, b1, bufA, N);
    aggregate_kernel<<<gN16, THREADS, 0, stream>>>(bufA, dis, ebond1, edir1, row_ptr, dst_cnt,
                                                   entries, out, N);

    // layer 2 (ReLU fused into GEMM input read): out -> bufA -> out
    gemm64_kernel<true><<<gG, THREADS, 0, stream>>>(out, W2, b2, bufA, N);
    aggregate_kernel<<<gN16, THREADS, 0, stream>>>(bufA, dis, ebond2, edir2, row_ptr, dst_cnt,
                                                   entries, out, N);
}